// Round 1
// baseline (4136.966 us; speedup 1.0000x reference)
//
#include <hip/hip_runtime.h>

#define DIM 128
#define NCLS 40

__device__ __forceinline__ void fma4(float4& a, float s, const float4& w) {
    a.x = fmaf(s, w.x, a.x);
    a.y = fmaf(s, w.y, a.y);
    a.z = fmaf(s, w.z, a.z);
    a.w = fmaf(s, w.w, a.w);
}

__device__ __forceinline__ float4 mbr(float4 acc, float4 g, float id, float4 bq) {
    // relu(acc + g*id + bq)
    float4 r;
    r.x = fmaxf(fmaf(g.x, id, acc.x + bq.x), 0.f);
    r.y = fmaxf(fmaf(g.y, id, acc.y + bq.y), 0.f);
    r.z = fmaxf(fmaf(g.z, id, acc.z + bq.z), 0.f);
    r.w = fmaxf(fmaf(g.w, id, acc.w + bq.w), 0.f);
    return r;
}

// degree histogram: one atomicAdd per edge
__global__ __launch_bounds__(256) void deg_kernel(const int* __restrict__ dst,
                                                  float* __restrict__ deg, int E) {
    int e = blockIdx.x * 256 + threadIdx.x;
    if (e < E) atomicAdd(&deg[dst[e]], 1.0f);
}

// Y = X @ W  (W: 128x128 staged in LDS).  fuse=1: Y = relu(acc + Agg/max(deg,1) + bias)
// block 256 = 8 row-lanes x 32 col-quads; each thread: 2 rows x 4 cols.
__global__ __launch_bounds__(256) void gemm128_kernel(
    const float* __restrict__ X, const float* __restrict__ W,
    const float* __restrict__ Agg, const float* __restrict__ deg,
    const float* __restrict__ bias, float* __restrict__ Y, int n, int fuse)
{
    __shared__ float4 Ws4[DIM * 32];   // 64 KB
    const float4* W4 = (const float4*)W;
    for (int i = threadIdx.x; i < DIM * 32; i += 256) Ws4[i] = W4[i];
    __syncthreads();
    const int cq = threadIdx.x & 31;
    const int rl = threadIdx.x >> 5;
    for (int base = blockIdx.x * 16; base < n; base += gridDim.x * 16) {
        const int r0 = base + rl;          // n % 16 == 0 for N=100000
        const int r1 = base + rl + 8;
        const float* __restrict__ x0 = X + (size_t)r0 * DIM;
        const float* __restrict__ x1 = X + (size_t)r1 * DIM;
        float4 acc0 = make_float4(0.f, 0.f, 0.f, 0.f);
        float4 acc1 = make_float4(0.f, 0.f, 0.f, 0.f);
        #pragma unroll 4
        for (int k = 0; k < DIM; k += 4) {
            const float4 a = *(const float4*)(x0 + k);
            const float4 b = *(const float4*)(x1 + k);
            const float4 w0 = Ws4[(k + 0) * 32 + cq];
            const float4 w1 = Ws4[(k + 1) * 32 + cq];
            const float4 w2 = Ws4[(k + 2) * 32 + cq];
            const float4 w3 = Ws4[(k + 3) * 32 + cq];
            fma4(acc0, a.x, w0); fma4(acc0, a.y, w1);
            fma4(acc0, a.z, w2); fma4(acc0, a.w, w3);
            fma4(acc1, b.x, w0); fma4(acc1, b.y, w1);
            fma4(acc1, b.z, w2); fma4(acc1, b.w, w3);
        }
        if (fuse) {
            const float id0 = 1.0f / fmaxf(deg[r0], 1.0f);
            const float id1 = 1.0f / fmaxf(deg[r1], 1.0f);
            const float4 bq = ((const float4*)bias)[cq];
            const float4 g0 = ((const float4*)(Agg + (size_t)r0 * DIM))[cq];
            const float4 g1 = ((const float4*)(Agg + (size_t)r1 * DIM))[cq];
            acc0 = mbr(acc0, g0, id0, bq);
            acc1 = mbr(acc1, g1, id1, bq);
        }
        ((float4*)(Y + (size_t)r0 * DIM))[cq] = acc0;
        ((float4*)(Y + (size_t)r1 * DIM))[cq] = acc1;
    }
}

// B[dst] += Y[src], 128 floats/edge, 32 threads per edge (float4 each)
__global__ __launch_bounds__(256) void scatter128_kernel(
    const float* __restrict__ Y, const int* __restrict__ src,
    const int* __restrict__ dst, float* __restrict__ B, int E)
{
    int t = blockIdx.x * 256 + threadIdx.x;
    int e = t >> 5;
    if (e >= E) return;
    int q = t & 31;
    int s = src[e], d = dst[e];
    float4 v = ((const float4*)(Y + (size_t)s * DIM))[q];
    float* p = B + (size_t)d * DIM + (size_t)q * 4;
    atomicAdd(p + 0, v.x);
    atomicAdd(p + 1, v.y);
    atomicAdd(p + 2, v.z);
    atomicAdd(p + 3, v.w);
}

// Dg[dst] += C[src], 40 floats/edge, 10 threads per edge (float4 each)
__global__ __launch_bounds__(256) void scatter40_kernel(
    const float* __restrict__ C, const int* __restrict__ src,
    const int* __restrict__ dst, float* __restrict__ Dg, int E)
{
    int t = blockIdx.x * 256 + threadIdx.x;
    int e = t / 10;
    if (e >= E) return;
    int q = t - e * 10;
    int s = src[e], d = dst[e];
    float4 v = ((const float4*)(C + (size_t)s * NCLS))[q];
    float* p = Dg + (size_t)d * NCLS + (size_t)q * 4;
    atomicAdd(p + 0, v.x);
    atomicAdd(p + 1, v.y);
    atomicAdd(p + 2, v.z);
    atomicAdd(p + 3, v.w);
}

// C = H @ W2_l  (128x40, W in LDS). block 320 = 40 cols x 8 row-groups; 4 rows/thread.
__global__ __launch_bounds__(320) void y2_kernel(
    const float* __restrict__ H, const float* __restrict__ W,
    float* __restrict__ C, int n)
{
    __shared__ float Ws[DIM * NCLS];   // 20 KB
    for (int i = threadIdx.x; i < DIM * NCLS; i += 320) Ws[i] = W[i];
    __syncthreads();
    const int col = threadIdx.x % NCLS;
    const int ry  = threadIdx.x / NCLS;   // 0..7
    for (int base = blockIdx.x * 32; base < n; base += gridDim.x * 32) {
        const int r = base + ry * 4;      // n % 32 == 0 for N=100000
        const float* __restrict__ h0 = H + (size_t)(r + 0) * DIM;
        const float* __restrict__ h1 = H + (size_t)(r + 1) * DIM;
        const float* __restrict__ h2 = H + (size_t)(r + 2) * DIM;
        const float* __restrict__ h3 = H + (size_t)(r + 3) * DIM;
        float a0 = 0.f, a1 = 0.f, a2 = 0.f, a3 = 0.f;
        #pragma unroll 4
        for (int k = 0; k < DIM; k += 4) {
            const float4 v0 = *(const float4*)(h0 + k);
            const float4 v1 = *(const float4*)(h1 + k);
            const float4 v2 = *(const float4*)(h2 + k);
            const float4 v3 = *(const float4*)(h3 + k);
            const float w0 = Ws[(k + 0) * NCLS + col];
            const float w1 = Ws[(k + 1) * NCLS + col];
            const float w2 = Ws[(k + 2) * NCLS + col];
            const float w3 = Ws[(k + 3) * NCLS + col];
            a0 = fmaf(v0.x, w0, fmaf(v0.y, w1, fmaf(v0.z, w2, fmaf(v0.w, w3, a0))));
            a1 = fmaf(v1.x, w0, fmaf(v1.y, w1, fmaf(v1.z, w2, fmaf(v1.w, w3, a1))));
            a2 = fmaf(v2.x, w0, fmaf(v2.y, w1, fmaf(v2.z, w2, fmaf(v2.w, w3, a2))));
            a3 = fmaf(v3.x, w0, fmaf(v3.y, w1, fmaf(v3.z, w2, fmaf(v3.w, w3, a3))));
        }
        C[(size_t)(r + 0) * NCLS + col] = a0;
        C[(size_t)(r + 1) * NCLS + col] = a1;
        C[(size_t)(r + 2) * NCLS + col] = a2;
        C[(size_t)(r + 3) * NCLS + col] = a3;
    }
}

// out = softmax(Agg/max(deg,1) + b2 + H @ W2_r), one thread per node (40 logits in regs)
__global__ __launch_bounds__(256) void final_kernel(
    const float* __restrict__ H, const float* __restrict__ Agg,
    const float* __restrict__ deg, const float* __restrict__ W,
    const float* __restrict__ b2, float* __restrict__ out, int n)
{
    int nd = blockIdx.x * 256 + threadIdx.x;
    if (nd >= n) return;
    float lg[NCLS];
    const float id = 1.0f / fmaxf(deg[nd], 1.0f);
    const float* __restrict__ ag = Agg + (size_t)nd * NCLS;
    #pragma unroll
    for (int c = 0; c < NCLS; ++c) lg[c] = fmaf(ag[c], id, b2[c]);
    const float* __restrict__ h = H + (size_t)nd * DIM;
    for (int k = 0; k < DIM; k += 4) {
        const float4 hv = *(const float4*)(h + k);
        const float* __restrict__ w0 = W + (size_t)(k + 0) * NCLS;  // uniform -> s_load
        const float* __restrict__ w1 = W + (size_t)(k + 1) * NCLS;
        const float* __restrict__ w2 = W + (size_t)(k + 2) * NCLS;
        const float* __restrict__ w3 = W + (size_t)(k + 3) * NCLS;
        #pragma unroll
        for (int c = 0; c < NCLS; ++c) {
            float acc = lg[c];
            acc = fmaf(hv.x, w0[c], acc);
            acc = fmaf(hv.y, w1[c], acc);
            acc = fmaf(hv.z, w2[c], acc);
            acc = fmaf(hv.w, w3[c], acc);
            lg[c] = acc;
        }
    }
    float m = lg[0];
    #pragma unroll
    for (int c = 1; c < NCLS; ++c) m = fmaxf(m, lg[c]);
    float s = 0.f;
    #pragma unroll
    for (int c = 0; c < NCLS; ++c) { lg[c] = __expf(lg[c] - m); s += lg[c]; }
    const float inv = 1.0f / s;
    float* __restrict__ o = out + (size_t)nd * NCLS;
    #pragma unroll
    for (int c = 0; c < NCLS; ++c) o[c] = lg[c] * inv;
}

extern "C" void kernel_launch(void* const* d_in, const int* in_sizes, int n_in,
                              void* d_out, int out_size, void* d_ws, size_t ws_size,
                              hipStream_t stream) {
    const float* x   = (const float*)d_in[0];
    const int*   ei  = (const int*)d_in[1];
    const float* W1l = (const float*)d_in[2];
    const float* W1r = (const float*)d_in[3];
    const float* b1  = (const float*)d_in[4];
    const float* W2l = (const float*)d_in[5];
    const float* W2r = (const float*)d_in[6];
    const float* b2  = (const float*)d_in[7];
    float* out = (float*)d_out;

    const int n = in_sizes[0] / DIM;   // 100000
    const int E = in_sizes[1] / 2;     // 1600000
    const int* src = ei;
    const int* dst = ei + E;

    // workspace layout (floats): A[n*128] | B[n*128] | C[n*40] | deg[n]
    float* A   = (float*)d_ws;                 // y1, then h
    float* B   = A + (size_t)n * DIM;          // layer-1 aggregation
    float* C   = B + (size_t)n * DIM;          // y2 = h @ W2_l
    float* deg = C + (size_t)n * NCLS;
    float* Dg  = out;                          // layer-2 aggregation accumulates in d_out

    hipMemsetAsync(B,   0, (size_t)n * DIM * sizeof(float), stream);
    hipMemsetAsync(Dg,  0, (size_t)n * NCLS * sizeof(float), stream);
    hipMemsetAsync(deg, 0, (size_t)n * sizeof(float), stream);

    deg_kernel<<<(E + 255) / 256, 256, 0, stream>>>(dst, deg, E);

    // y1 = x @ W1_l
    gemm128_kernel<<<512, 256, 0, stream>>>(x, W1l, nullptr, nullptr, nullptr, A, n, 0);

    // B[dst] += y1[src]
    {
        long long t = (long long)E * 32;
        scatter128_kernel<<<(int)((t + 255) / 256), 256, 0, stream>>>(A, src, dst, B, E);
    }

    // h = relu(B/deg + b1 + x @ W1_r)  (overwrites A)
    gemm128_kernel<<<512, 256, 0, stream>>>(x, W1r, B, deg, b1, A, n, 1);

    // C = h @ W2_l
    y2_kernel<<<625, 320, 0, stream>>>(A, W2l, C, n);

    // Dg[dst] += C[src]
    {
        long long t = (long long)E * 10;
        scatter40_kernel<<<(int)((t + 255) / 256), 256, 0, stream>>>(C, src, dst, Dg, E);
    }

    // out = softmax(Dg/deg + b2 + h @ W2_r)
    final_kernel<<<(n + 255) / 256, 256, 0, stream>>>(A, Dg, deg, W2r, b2, out, n);
}

// Round 2
// 700.011 us; speedup vs baseline: 5.9099x; 5.9099x over previous
//
#include <hip/hip_runtime.h>

#define DIM 128
#define NCLS 40
#define SCAN_B 1024

__device__ __forceinline__ void fma4(float4& a, float s, const float4& w) {
    a.x = fmaf(s, w.x, a.x);
    a.y = fmaf(s, w.y, a.y);
    a.z = fmaf(s, w.z, a.z);
    a.w = fmaf(s, w.w, a.w);
}

// ---------------- CSR build ----------------

__global__ __launch_bounds__(256) void hist_kernel(const int* __restrict__ dst,
                                                   int* __restrict__ deg, int E) {
    int e = blockIdx.x * 256 + threadIdx.x;
    if (e < E) atomicAdd(&deg[dst[e]], 1);
}

// per-block sums of 1024-chunks
__global__ __launch_bounds__(256) void scan1_kernel(const int* __restrict__ deg,
                                                    int* __restrict__ bsum, int n) {
    __shared__ int sh[256];
    int base = blockIdx.x * SCAN_B;
    int s = 0;
    for (int i = threadIdx.x; i < SCAN_B; i += 256) {
        int idx = base + i;
        if (idx < n) s += deg[idx];
    }
    sh[threadIdx.x] = s;
    __syncthreads();
    for (int off = 128; off > 0; off >>= 1) {
        if (threadIdx.x < off) sh[threadIdx.x] += sh[threadIdx.x + off];
        __syncthreads();
    }
    if (threadIdx.x == 0) bsum[blockIdx.x] = sh[0];
}

// exclusive scan of block sums (nb ~ 98, single thread is fine) + write row_ptr[n]
__global__ __launch_bounds__(64) void scan2_kernel(int* __restrict__ bsum, int nb,
                                                   int* __restrict__ row_ptr, int n) {
    if (threadIdx.x == 0 && blockIdx.x == 0) {
        int acc = 0;
        for (int b = 0; b < nb; ++b) { int v = bsum[b]; bsum[b] = acc; acc += v; }
        row_ptr[n] = acc;   // == E
    }
}

// exclusive scan within each 1024-chunk + block offset -> row_ptr
__global__ __launch_bounds__(SCAN_B) void scan3_kernel(const int* __restrict__ deg,
                                                       const int* __restrict__ bsum,
                                                       int* __restrict__ row_ptr, int n) {
    __shared__ int sh[SCAN_B];
    int i = blockIdx.x * SCAN_B + threadIdx.x;
    int v = (i < n) ? deg[i] : 0;
    sh[threadIdx.x] = v;
    __syncthreads();
    for (int off = 1; off < SCAN_B; off <<= 1) {
        int t = (threadIdx.x >= off) ? sh[threadIdx.x - off] : 0;
        __syncthreads();
        sh[threadIdx.x] += t;
        __syncthreads();
    }
    if (i < n) row_ptr[i] = sh[threadIdx.x] - v + bsum[blockIdx.x];
}

// eidx[row_ptr[d] + pos[d]++] = src[e]
__global__ __launch_bounds__(256) void fill_kernel(const int* __restrict__ src,
                                                   const int* __restrict__ dst,
                                                   const int* __restrict__ row_ptr,
                                                   int* __restrict__ pos,
                                                   int* __restrict__ eidx, int E) {
    int e = blockIdx.x * 256 + threadIdx.x;
    if (e >= E) return;
    int d = dst[e];
    int p = row_ptr[d] + atomicAdd(&pos[d], 1);
    eidx[p] = src[e];
}

// ---------------- compute ----------------

// Y = X @ W  (W: 128x128 staged in LDS).  fuse=1: Y = relu(acc + Agg + bias)
// block 256 = 8 row-lanes x 32 col-quads; each thread: 2 rows x 4 cols.
__global__ __launch_bounds__(256) void gemm128_kernel(
    const float* __restrict__ X, const float* __restrict__ W,
    const float* __restrict__ Agg, const float* __restrict__ bias,
    float* __restrict__ Y, int n, int fuse)
{
    __shared__ float4 Ws4[DIM * 32];   // 64 KB
    const float4* W4 = (const float4*)W;
    for (int i = threadIdx.x; i < DIM * 32; i += 256) Ws4[i] = W4[i];
    __syncthreads();
    const int cq = threadIdx.x & 31;
    const int rl = threadIdx.x >> 5;
    for (int base = blockIdx.x * 16; base < n; base += gridDim.x * 16) {
        const int r0 = base + rl;          // n % 16 == 0 for N=100000
        const int r1 = base + rl + 8;
        const float* __restrict__ x0 = X + (size_t)r0 * DIM;
        const float* __restrict__ x1 = X + (size_t)r1 * DIM;
        float4 acc0 = make_float4(0.f, 0.f, 0.f, 0.f);
        float4 acc1 = make_float4(0.f, 0.f, 0.f, 0.f);
        #pragma unroll 4
        for (int k = 0; k < DIM; k += 4) {
            const float4 a = *(const float4*)(x0 + k);
            const float4 b = *(const float4*)(x1 + k);
            const float4 w0 = Ws4[(k + 0) * 32 + cq];
            const float4 w1 = Ws4[(k + 1) * 32 + cq];
            const float4 w2 = Ws4[(k + 2) * 32 + cq];
            const float4 w3 = Ws4[(k + 3) * 32 + cq];
            fma4(acc0, a.x, w0); fma4(acc0, a.y, w1);
            fma4(acc0, a.z, w2); fma4(acc0, a.w, w3);
            fma4(acc1, b.x, w0); fma4(acc1, b.y, w1);
            fma4(acc1, b.z, w2); fma4(acc1, b.w, w3);
        }
        if (fuse) {
            const float4 bq = ((const float4*)bias)[cq];
            const float4 g0 = ((const float4*)(Agg + (size_t)r0 * DIM))[cq];
            const float4 g1 = ((const float4*)(Agg + (size_t)r1 * DIM))[cq];
            acc0.x = fmaxf(acc0.x + g0.x + bq.x, 0.f);
            acc0.y = fmaxf(acc0.y + g0.y + bq.y, 0.f);
            acc0.z = fmaxf(acc0.z + g0.z + bq.z, 0.f);
            acc0.w = fmaxf(acc0.w + g0.w + bq.w, 0.f);
            acc1.x = fmaxf(acc1.x + g1.x + bq.x, 0.f);
            acc1.y = fmaxf(acc1.y + g1.y + bq.y, 0.f);
            acc1.z = fmaxf(acc1.z + g1.z + bq.z, 0.f);
            acc1.w = fmaxf(acc1.w + g1.w + bq.w, 0.f);
        }
        ((float4*)(Y + (size_t)r0 * DIM))[cq] = acc0;
        ((float4*)(Y + (size_t)r1 * DIM))[cq] = acc1;
    }
}

// B[node] = mean over CSR neighbors of Y[src]; 32 lanes per node (float4 each)
__global__ __launch_bounds__(256) void gather128_kernel(
    const float* __restrict__ Y, const int* __restrict__ row_ptr,
    const int* __restrict__ eidx, float* __restrict__ B, int n)
{
    int t = blockIdx.x * 256 + threadIdx.x;
    int node = t >> 5;
    if (node >= n) return;
    int q = t & 31;
    int j  = row_ptr[node];
    int je = row_ptr[node + 1];
    const float id = 1.0f / fmaxf((float)(je - j), 1.0f);
    float4 acc = make_float4(0.f, 0.f, 0.f, 0.f);
    for (; j + 1 < je; j += 2) {
        int s0 = eidx[j], s1 = eidx[j + 1];
        float4 v0 = ((const float4*)(Y + (size_t)s0 * DIM))[q];
        float4 v1 = ((const float4*)(Y + (size_t)s1 * DIM))[q];
        acc.x += v0.x + v1.x;
        acc.y += v0.y + v1.y;
        acc.z += v0.z + v1.z;
        acc.w += v0.w + v1.w;
    }
    if (j < je) {
        int s0 = eidx[j];
        float4 v0 = ((const float4*)(Y + (size_t)s0 * DIM))[q];
        acc.x += v0.x; acc.y += v0.y; acc.z += v0.z; acc.w += v0.w;
    }
    acc.x *= id; acc.y *= id; acc.z *= id; acc.w *= id;
    ((float4*)(B + (size_t)node * DIM))[q] = acc;
}

// Dg[node] = mean over CSR neighbors of C[src]; 10 lanes per node (float4 each)
__global__ __launch_bounds__(256) void gather40_kernel(
    const float* __restrict__ C, const int* __restrict__ row_ptr,
    const int* __restrict__ eidx, float* __restrict__ Dg, int n)
{
    int t = blockIdx.x * 256 + threadIdx.x;
    int node = t / 10;
    if (node >= n) return;
    int q = t - node * 10;
    int j  = row_ptr[node];
    int je = row_ptr[node + 1];
    const float id = 1.0f / fmaxf((float)(je - j), 1.0f);
    float4 acc = make_float4(0.f, 0.f, 0.f, 0.f);
    for (; j + 1 < je; j += 2) {
        int s0 = eidx[j], s1 = eidx[j + 1];
        float4 v0 = ((const float4*)(C + (size_t)s0 * NCLS))[q];
        float4 v1 = ((const float4*)(C + (size_t)s1 * NCLS))[q];
        acc.x += v0.x + v1.x;
        acc.y += v0.y + v1.y;
        acc.z += v0.z + v1.z;
        acc.w += v0.w + v1.w;
    }
    if (j < je) {
        int s0 = eidx[j];
        float4 v0 = ((const float4*)(C + (size_t)s0 * NCLS))[q];
        acc.x += v0.x; acc.y += v0.y; acc.z += v0.z; acc.w += v0.w;
    }
    acc.x *= id; acc.y *= id; acc.z *= id; acc.w *= id;
    ((float4*)(Dg + (size_t)node * NCLS))[q] = acc;
}

// C = H @ W2_l  (128x40, W in LDS). block 320 = 40 cols x 8 row-groups; 4 rows/thread.
__global__ __launch_bounds__(320) void y2_kernel(
    const float* __restrict__ H, const float* __restrict__ W,
    float* __restrict__ C, int n)
{
    __shared__ float Ws[DIM * NCLS];   // 20 KB
    for (int i = threadIdx.x; i < DIM * NCLS; i += 320) Ws[i] = W[i];
    __syncthreads();
    const int col = threadIdx.x % NCLS;
    const int ry  = threadIdx.x / NCLS;   // 0..7
    for (int base = blockIdx.x * 32; base < n; base += gridDim.x * 32) {
        const int r = base + ry * 4;      // n % 32 == 0 for N=100000
        const float* __restrict__ h0 = H + (size_t)(r + 0) * DIM;
        const float* __restrict__ h1 = H + (size_t)(r + 1) * DIM;
        const float* __restrict__ h2 = H + (size_t)(r + 2) * DIM;
        const float* __restrict__ h3 = H + (size_t)(r + 3) * DIM;
        float a0 = 0.f, a1 = 0.f, a2 = 0.f, a3 = 0.f;
        #pragma unroll 4
        for (int k = 0; k < DIM; k += 4) {
            const float4 v0 = *(const float4*)(h0 + k);
            const float4 v1 = *(const float4*)(h1 + k);
            const float4 v2 = *(const float4*)(h2 + k);
            const float4 v3 = *(const float4*)(h3 + k);
            const float w0 = Ws[(k + 0) * NCLS + col];
            const float w1 = Ws[(k + 1) * NCLS + col];
            const float w2 = Ws[(k + 2) * NCLS + col];
            const float w3 = Ws[(k + 3) * NCLS + col];
            a0 = fmaf(v0.x, w0, fmaf(v0.y, w1, fmaf(v0.z, w2, fmaf(v0.w, w3, a0))));
            a1 = fmaf(v1.x, w0, fmaf(v1.y, w1, fmaf(v1.z, w2, fmaf(v1.w, w3, a1))));
            a2 = fmaf(v2.x, w0, fmaf(v2.y, w1, fmaf(v2.z, w2, fmaf(v2.w, w3, a2))));
            a3 = fmaf(v3.x, w0, fmaf(v3.y, w1, fmaf(v3.z, w2, fmaf(v3.w, w3, a3))));
        }
        C[(size_t)(r + 0) * NCLS + col] = a0;
        C[(size_t)(r + 1) * NCLS + col] = a1;
        C[(size_t)(r + 2) * NCLS + col] = a2;
        C[(size_t)(r + 3) * NCLS + col] = a3;
    }
}

// out = softmax(Agg + b2 + H @ W2_r), one thread per node (40 logits in regs)
__global__ __launch_bounds__(256) void final_kernel(
    const float* __restrict__ H, const float* __restrict__ Agg,
    const float* __restrict__ W, const float* __restrict__ b2,
    float* __restrict__ out, int n)
{
    int nd = blockIdx.x * 256 + threadIdx.x;
    if (nd >= n) return;
    float lg[NCLS];
    const float* __restrict__ ag = Agg + (size_t)nd * NCLS;
    #pragma unroll
    for (int c = 0; c < NCLS; ++c) lg[c] = ag[c] + b2[c];
    const float* __restrict__ h = H + (size_t)nd * DIM;
    for (int k = 0; k < DIM; k += 4) {
        const float4 hv = *(const float4*)(h + k);
        const float* __restrict__ w0 = W + (size_t)(k + 0) * NCLS;  // uniform -> s_load
        const float* __restrict__ w1 = W + (size_t)(k + 1) * NCLS;
        const float* __restrict__ w2 = W + (size_t)(k + 2) * NCLS;
        const float* __restrict__ w3 = W + (size_t)(k + 3) * NCLS;
        #pragma unroll
        for (int c = 0; c < NCLS; ++c) {
            float acc = lg[c];
            acc = fmaf(hv.x, w0[c], acc);
            acc = fmaf(hv.y, w1[c], acc);
            acc = fmaf(hv.z, w2[c], acc);
            acc = fmaf(hv.w, w3[c], acc);
            lg[c] = acc;
        }
    }
    float m = lg[0];
    #pragma unroll
    for (int c = 1; c < NCLS; ++c) m = fmaxf(m, lg[c]);
    float s = 0.f;
    #pragma unroll
    for (int c = 0; c < NCLS; ++c) { lg[c] = __expf(lg[c] - m); s += lg[c]; }
    const float inv = 1.0f / s;
    float* __restrict__ o = out + (size_t)nd * NCLS;
    #pragma unroll
    for (int c = 0; c < NCLS; ++c) o[c] = lg[c] * inv;
}

extern "C" void kernel_launch(void* const* d_in, const int* in_sizes, int n_in,
                              void* d_out, int out_size, void* d_ws, size_t ws_size,
                              hipStream_t stream) {
    const float* x   = (const float*)d_in[0];
    const int*   ei  = (const int*)d_in[1];
    const float* W1l = (const float*)d_in[2];
    const float* W1r = (const float*)d_in[3];
    const float* b1  = (const float*)d_in[4];
    const float* W2l = (const float*)d_in[5];
    const float* W2r = (const float*)d_in[6];
    const float* b2  = (const float*)d_in[7];
    float* out = (float*)d_out;

    const int n = in_sizes[0] / DIM;   // 100000
    const int E = in_sizes[1] / 2;     // 1600000
    const int* src = ei;
    const int* dst = ei + E;
    const int nb = (n + SCAN_B - 1) / SCAN_B;   // 98 scan blocks

    // workspace layout (4-byte units):
    //   A[n*128] | B[n*128] | eidx[E] | row_ptr[n+1] | deg[n] | pos[n] | bsum[128]
    // C (n*40) and Dg (n*40) alias the B region once B has been consumed.
    float* A       = (float*)d_ws;               // y1, then h
    float* B       = A + (size_t)n * DIM;        // layer-1 mean aggregation
    int*   eidx    = (int*)(B + (size_t)n * DIM);
    int*   row_ptr = eidx + E;
    int*   deg     = row_ptr + (n + 1);
    int*   pos     = deg + n;
    int*   bsum    = pos + n;
    float* C       = B;                          // y2 = h @ W2_l (reuses B)
    float* Dg      = B + (size_t)n * NCLS;       // layer-2 mean aggregation

    hipMemsetAsync(deg, 0, (size_t)n * sizeof(int), stream);
    hipMemsetAsync(pos, 0, (size_t)n * sizeof(int), stream);

    // --- CSR build (sorted-by-dst edge buckets) ---
    hist_kernel <<<(E + 255) / 256, 256, 0, stream>>>(dst, deg, E);
    scan1_kernel<<<nb, 256, 0, stream>>>(deg, bsum, n);
    scan2_kernel<<<1, 64, 0, stream>>>(bsum, nb, row_ptr, n);
    scan3_kernel<<<nb, SCAN_B, 0, stream>>>(deg, bsum, row_ptr, n);
    fill_kernel <<<(E + 255) / 256, 256, 0, stream>>>(src, dst, row_ptr, pos, eidx, E);

    // --- layer 1 ---
    // y1 = x @ W1_l
    gemm128_kernel<<<512, 256, 0, stream>>>(x, W1l, nullptr, nullptr, A, n, 0);
    // B = mean_{src in N(dst)} y1[src]
    {
        long long t = (long long)n * 32;
        gather128_kernel<<<(int)((t + 255) / 256), 256, 0, stream>>>(A, row_ptr, eidx, B, n);
    }
    // h = relu(x @ W1_r + B + b1)   (overwrites A)
    gemm128_kernel<<<512, 256, 0, stream>>>(x, W1r, B, b1, A, n, 1);

    // --- layer 2 ---
    // C = h @ W2_l  (reuses B region)
    y2_kernel<<<625, 320, 0, stream>>>(A, W2l, C, n);
    // Dg = mean_{src in N(dst)} C[src]
    {
        long long t = (long long)n * 10;
        gather40_kernel<<<(int)((t + 255) / 256), 256, 0, stream>>>(C, row_ptr, eidx, Dg, n);
    }
    // out = softmax(Dg + b2 + h @ W2_r)
    final_kernel<<<(n + 255) / 256, 256, 0, stream>>>(A, Dg, W2r, b2, out, n);
}

// Round 3
// 629.886 us; speedup vs baseline: 6.5678x; 1.1113x over previous
//
#include <hip/hip_runtime.h>

#define DIM 128
#define NCLS 40
#define SCAN_B 1024

typedef unsigned short ushort_t;

__device__ __forceinline__ ushort_t f2b(float f) {
    union { float f; unsigned u; } v; v.f = f;
    unsigned r = v.u + 0x7FFFu + ((v.u >> 16) & 1u);   // round-to-nearest-even
    return (ushort_t)(r >> 16);
}

__device__ __forceinline__ float b2f(ushort_t b) {
    union { unsigned u; float f; } v; v.u = ((unsigned)b) << 16;
    return v.f;
}

__device__ __forceinline__ void fma4(float4& a, float s, const float4& w) {
    a.x = fmaf(s, w.x, a.x);
    a.y = fmaf(s, w.y, a.y);
    a.z = fmaf(s, w.z, a.z);
    a.w = fmaf(s, w.w, a.w);
}

// ---------------- CSR build ----------------

__global__ __launch_bounds__(256) void hist_kernel(const int* __restrict__ dst,
                                                   int* __restrict__ deg, int E) {
    int e = blockIdx.x * 256 + threadIdx.x;
    if (e < E) atomicAdd(&deg[dst[e]], 1);
}

// per-block sums of 1024-chunks
__global__ __launch_bounds__(256) void scan1_kernel(const int* __restrict__ deg,
                                                    int* __restrict__ bsum, int n) {
    __shared__ int sh[256];
    int base = blockIdx.x * SCAN_B;
    int s = 0;
    for (int i = threadIdx.x; i < SCAN_B; i += 256) {
        int idx = base + i;
        if (idx < n) s += deg[idx];
    }
    sh[threadIdx.x] = s;
    __syncthreads();
    for (int off = 128; off > 0; off >>= 1) {
        if (threadIdx.x < off) sh[threadIdx.x] += sh[threadIdx.x + off];
        __syncthreads();
    }
    if (threadIdx.x == 0) bsum[blockIdx.x] = sh[0];
}

// exclusive scan of block sums (nb ~ 98, single thread is fine) + write row_ptr[n]
__global__ __launch_bounds__(64) void scan2_kernel(int* __restrict__ bsum, int nb,
                                                   int* __restrict__ row_ptr, int n) {
    if (threadIdx.x == 0 && blockIdx.x == 0) {
        int acc = 0;
        for (int b = 0; b < nb; ++b) { int v = bsum[b]; bsum[b] = acc; acc += v; }
        row_ptr[n] = acc;   // == E
    }
}

// exclusive scan within each 1024-chunk + block offset -> row_ptr, and pos = row_ptr
__global__ __launch_bounds__(SCAN_B) void scan3_kernel(const int* __restrict__ deg,
                                                       const int* __restrict__ bsum,
                                                       int* __restrict__ row_ptr,
                                                       int* __restrict__ pos, int n) {
    __shared__ int sh[SCAN_B];
    int i = blockIdx.x * SCAN_B + threadIdx.x;
    int v = (i < n) ? deg[i] : 0;
    sh[threadIdx.x] = v;
    __syncthreads();
    for (int off = 1; off < SCAN_B; off <<= 1) {
        int t = (threadIdx.x >= off) ? sh[threadIdx.x - off] : 0;
        __syncthreads();
        sh[threadIdx.x] += t;
        __syncthreads();
    }
    if (i < n) {
        int rp = sh[threadIdx.x] - v + bsum[blockIdx.x];
        row_ptr[i] = rp;
        pos[i] = rp;        // fill bumps pos directly -> absolute slot, no row_ptr read
    }
}

// eidx[atomicAdd(&pos[d],1)] = src[e], bucketed by dst range so that the
// scattered eidx stores stay within an ~E/8 * 4B window (L2-resident, merged
// evictions) per pass. Buckets touch disjoint pos/eidx entries -> no sync needed.
__global__ __launch_bounds__(256) void fill_kernel(const int* __restrict__ src,
                                                   const int* __restrict__ dst,
                                                   int* __restrict__ pos,
                                                   int* __restrict__ eidx,
                                                   int E, int n) {
    const int nbuck = 8;
    const int bsz = (n + nbuck - 1) / nbuck;
    const int tid = blockIdx.x * 256 + threadIdx.x;
    const int stride = gridDim.x * 256;
    for (int b = 0; b < nbuck; ++b) {
        const int lo = b * bsz;
        const int hi = lo + bsz;
        for (int e = tid; e < E; e += stride) {
            int d = dst[e];
            if (d >= lo && d < hi) {
                int p = atomicAdd(&pos[d], 1);
                eidx[p] = src[e];
            }
        }
    }
}

// ---------------- compute ----------------

// mode 0: Ybf (bf16) = X @ W            (store packed bf16, no epilogue)
// mode 1: Y   (fp32) = relu(X @ W + b2f(Aggbf) + bias)
// block 256 = 8 row-lanes x 32 col-quads; each thread: 2 rows x 4 cols.
__global__ __launch_bounds__(256) void gemm128_kernel(
    const float* __restrict__ X, const float* __restrict__ W,
    const ushort_t* __restrict__ Aggbf, const float* __restrict__ bias,
    float* __restrict__ Y, ushort_t* __restrict__ Ybf, int n, int fuse)
{
    __shared__ float4 Ws4[DIM * 32];   // 64 KB
    const float4* W4 = (const float4*)W;
    for (int i = threadIdx.x; i < DIM * 32; i += 256) Ws4[i] = W4[i];
    __syncthreads();
    const int cq = threadIdx.x & 31;
    const int rl = threadIdx.x >> 5;
    for (int base = blockIdx.x * 16; base < n; base += gridDim.x * 16) {
        const int r0 = base + rl;          // n % 16 == 0 for N=100000
        const int r1 = base + rl + 8;
        const float* __restrict__ x0 = X + (size_t)r0 * DIM;
        const float* __restrict__ x1 = X + (size_t)r1 * DIM;
        float4 acc0 = make_float4(0.f, 0.f, 0.f, 0.f);
        float4 acc1 = make_float4(0.f, 0.f, 0.f, 0.f);
        #pragma unroll 4
        for (int k = 0; k < DIM; k += 4) {
            const float4 a = *(const float4*)(x0 + k);
            const float4 b = *(const float4*)(x1 + k);
            const float4 w0 = Ws4[(k + 0) * 32 + cq];
            const float4 w1 = Ws4[(k + 1) * 32 + cq];
            const float4 w2 = Ws4[(k + 2) * 32 + cq];
            const float4 w3 = Ws4[(k + 3) * 32 + cq];
            fma4(acc0, a.x, w0); fma4(acc0, a.y, w1);
            fma4(acc0, a.z, w2); fma4(acc0, a.w, w3);
            fma4(acc1, b.x, w0); fma4(acc1, b.y, w1);
            fma4(acc1, b.z, w2); fma4(acc1, b.w, w3);
        }
        if (fuse) {
            const float4 bq = ((const float4*)bias)[cq];
            const ushort4 g0u = ((const ushort4*)(Aggbf + (size_t)r0 * DIM))[cq];
            const ushort4 g1u = ((const ushort4*)(Aggbf + (size_t)r1 * DIM))[cq];
            acc0.x = fmaxf(acc0.x + b2f(g0u.x) + bq.x, 0.f);
            acc0.y = fmaxf(acc0.y + b2f(g0u.y) + bq.y, 0.f);
            acc0.z = fmaxf(acc0.z + b2f(g0u.z) + bq.z, 0.f);
            acc0.w = fmaxf(acc0.w + b2f(g0u.w) + bq.w, 0.f);
            acc1.x = fmaxf(acc1.x + b2f(g1u.x) + bq.x, 0.f);
            acc1.y = fmaxf(acc1.y + b2f(g1u.y) + bq.y, 0.f);
            acc1.z = fmaxf(acc1.z + b2f(g1u.z) + bq.z, 0.f);
            acc1.w = fmaxf(acc1.w + b2f(g1u.w) + bq.w, 0.f);
            ((float4*)(Y + (size_t)r0 * DIM))[cq] = acc0;
            ((float4*)(Y + (size_t)r1 * DIM))[cq] = acc1;
        } else {
            ushort4 o0, o1;
            o0.x = f2b(acc0.x); o0.y = f2b(acc0.y); o0.z = f2b(acc0.z); o0.w = f2b(acc0.w);
            o1.x = f2b(acc1.x); o1.y = f2b(acc1.y); o1.z = f2b(acc1.z); o1.w = f2b(acc1.w);
            ((ushort4*)(Ybf + (size_t)r0 * DIM))[cq] = o0;
            ((ushort4*)(Ybf + (size_t)r1 * DIM))[cq] = o1;
        }
    }
}

// Bbf[node] = mean over CSR neighbors of Ybf[src] (bf16 in, fp32 accum, bf16 out)
// 32 lanes per node, ushort4 (8B) per lane -> 256B/edge coalesced
__global__ __launch_bounds__(256) void gather128_kernel(
    const ushort_t* __restrict__ Ybf, const int* __restrict__ row_ptr,
    const int* __restrict__ eidx, ushort_t* __restrict__ Bbf, int n)
{
    int t = blockIdx.x * 256 + threadIdx.x;
    int node = t >> 5;
    if (node >= n) return;
    int q = t & 31;
    int j  = row_ptr[node];
    int je = row_ptr[node + 1];
    const float id = 1.0f / fmaxf((float)(je - j), 1.0f);
    float4 acc = make_float4(0.f, 0.f, 0.f, 0.f);
    for (; j + 1 < je; j += 2) {
        int s0 = eidx[j], s1 = eidx[j + 1];
        ushort4 v0 = ((const ushort4*)(Ybf + (size_t)s0 * DIM))[q];
        ushort4 v1 = ((const ushort4*)(Ybf + (size_t)s1 * DIM))[q];
        acc.x += b2f(v0.x) + b2f(v1.x);
        acc.y += b2f(v0.y) + b2f(v1.y);
        acc.z += b2f(v0.z) + b2f(v1.z);
        acc.w += b2f(v0.w) + b2f(v1.w);
    }
    if (j < je) {
        int s0 = eidx[j];
        ushort4 v0 = ((const ushort4*)(Ybf + (size_t)s0 * DIM))[q];
        acc.x += b2f(v0.x); acc.y += b2f(v0.y); acc.z += b2f(v0.z); acc.w += b2f(v0.w);
    }
    ushort4 o;
    o.x = f2b(acc.x * id); o.y = f2b(acc.y * id);
    o.z = f2b(acc.z * id); o.w = f2b(acc.w * id);
    ((ushort4*)(Bbf + (size_t)node * DIM))[q] = o;
}

// Dg[node] = mean over CSR neighbors of C[src]; 10 lanes per node (float4 each)
__global__ __launch_bounds__(256) void gather40_kernel(
    const float* __restrict__ C, const int* __restrict__ row_ptr,
    const int* __restrict__ eidx, float* __restrict__ Dg, int n)
{
    int t = blockIdx.x * 256 + threadIdx.x;
    int node = t / 10;
    if (node >= n) return;
    int q = t - node * 10;
    int j  = row_ptr[node];
    int je = row_ptr[node + 1];
    const float id = 1.0f / fmaxf((float)(je - j), 1.0f);
    float4 acc = make_float4(0.f, 0.f, 0.f, 0.f);
    for (; j + 1 < je; j += 2) {
        int s0 = eidx[j], s1 = eidx[j + 1];
        float4 v0 = ((const float4*)(C + (size_t)s0 * NCLS))[q];
        float4 v1 = ((const float4*)(C + (size_t)s1 * NCLS))[q];
        acc.x += v0.x + v1.x;
        acc.y += v0.y + v1.y;
        acc.z += v0.z + v1.z;
        acc.w += v0.w + v1.w;
    }
    if (j < je) {
        int s0 = eidx[j];
        float4 v0 = ((const float4*)(C + (size_t)s0 * NCLS))[q];
        acc.x += v0.x; acc.y += v0.y; acc.z += v0.z; acc.w += v0.w;
    }
    acc.x *= id; acc.y *= id; acc.z *= id; acc.w *= id;
    ((float4*)(Dg + (size_t)node * NCLS))[q] = acc;
}

// C = H @ W2_l  (128x40, W in LDS). block 320 = 40 cols x 8 row-groups; 4 rows/thread.
__global__ __launch_bounds__(320) void y2_kernel(
    const float* __restrict__ H, const float* __restrict__ W,
    float* __restrict__ C, int n)
{
    __shared__ float Ws[DIM * NCLS];   // 20 KB
    for (int i = threadIdx.x; i < DIM * NCLS; i += 320) Ws[i] = W[i];
    __syncthreads();
    const int col = threadIdx.x % NCLS;
    const int ry  = threadIdx.x / NCLS;   // 0..7
    for (int base = blockIdx.x * 32; base < n; base += gridDim.x * 32) {
        const int r = base + ry * 4;      // n % 32 == 0 for N=100000
        const float* __restrict__ h0 = H + (size_t)(r + 0) * DIM;
        const float* __restrict__ h1 = H + (size_t)(r + 1) * DIM;
        const float* __restrict__ h2 = H + (size_t)(r + 2) * DIM;
        const float* __restrict__ h3 = H + (size_t)(r + 3) * DIM;
        float a0 = 0.f, a1 = 0.f, a2 = 0.f, a3 = 0.f;
        #pragma unroll 4
        for (int k = 0; k < DIM; k += 4) {
            const float4 v0 = *(const float4*)(h0 + k);
            const float4 v1 = *(const float4*)(h1 + k);
            const float4 v2 = *(const float4*)(h2 + k);
            const float4 v3 = *(const float4*)(h3 + k);
            const float w0 = Ws[(k + 0) * NCLS + col];
            const float w1 = Ws[(k + 1) * NCLS + col];
            const float w2 = Ws[(k + 2) * NCLS + col];
            const float w3 = Ws[(k + 3) * NCLS + col];
            a0 = fmaf(v0.x, w0, fmaf(v0.y, w1, fmaf(v0.z, w2, fmaf(v0.w, w3, a0))));
            a1 = fmaf(v1.x, w0, fmaf(v1.y, w1, fmaf(v1.z, w2, fmaf(v1.w, w3, a1))));
            a2 = fmaf(v2.x, w0, fmaf(v2.y, w1, fmaf(v2.z, w2, fmaf(v2.w, w3, a2))));
            a3 = fmaf(v3.x, w0, fmaf(v3.y, w1, fmaf(v3.z, w2, fmaf(v3.w, w3, a3))));
        }
        C[(size_t)(r + 0) * NCLS + col] = a0;
        C[(size_t)(r + 1) * NCLS + col] = a1;
        C[(size_t)(r + 2) * NCLS + col] = a2;
        C[(size_t)(r + 3) * NCLS + col] = a3;
    }
}

// out = softmax(Agg + b2 + H @ W2_r), one thread per node (40 logits in regs)
__global__ __launch_bounds__(256) void final_kernel(
    const float* __restrict__ H, const float* __restrict__ Agg,
    const float* __restrict__ W, const float* __restrict__ b2,
    float* __restrict__ out, int n)
{
    int nd = blockIdx.x * 256 + threadIdx.x;
    if (nd >= n) return;
    float lg[NCLS];
    const float* __restrict__ ag = Agg + (size_t)nd * NCLS;
    #pragma unroll
    for (int c = 0; c < NCLS; ++c) lg[c] = ag[c] + b2[c];
    const float* __restrict__ h = H + (size_t)nd * DIM;
    for (int k = 0; k < DIM; k += 4) {
        const float4 hv = *(const float4*)(h + k);
        const float* __restrict__ w0 = W + (size_t)(k + 0) * NCLS;  // uniform -> s_load
        const float* __restrict__ w1 = W + (size_t)(k + 1) * NCLS;
        const float* __restrict__ w2 = W + (size_t)(k + 2) * NCLS;
        const float* __restrict__ w3 = W + (size_t)(k + 3) * NCLS;
        #pragma unroll
        for (int c = 0; c < NCLS; ++c) {
            float acc = lg[c];
            acc = fmaf(hv.x, w0[c], acc);
            acc = fmaf(hv.y, w1[c], acc);
            acc = fmaf(hv.z, w2[c], acc);
            acc = fmaf(hv.w, w3[c], acc);
            lg[c] = acc;
        }
    }
    float m = lg[0];
    #pragma unroll
    for (int c = 1; c < NCLS; ++c) m = fmaxf(m, lg[c]);
    float s = 0.f;
    #pragma unroll
    for (int c = 0; c < NCLS; ++c) { lg[c] = __expf(lg[c] - m); s += lg[c]; }
    const float inv = 1.0f / s;
    float* __restrict__ o = out + (size_t)nd * NCLS;
    #pragma unroll
    for (int c = 0; c < NCLS; ++c) o[c] = lg[c] * inv;
}

extern "C" void kernel_launch(void* const* d_in, const int* in_sizes, int n_in,
                              void* d_out, int out_size, void* d_ws, size_t ws_size,
                              hipStream_t stream) {
    const float* x   = (const float*)d_in[0];
    const int*   ei  = (const int*)d_in[1];
    const float* W1l = (const float*)d_in[2];
    const float* W1r = (const float*)d_in[3];
    const float* b1  = (const float*)d_in[4];
    const float* W2l = (const float*)d_in[5];
    const float* W2r = (const float*)d_in[6];
    const float* b2  = (const float*)d_in[7];
    float* out = (float*)d_out;

    const int n = in_sizes[0] / DIM;   // 100000
    const int E = in_sizes[1] / 2;     // 1600000
    const int* src = ei;
    const int* dst = ei + E;
    const int nb = (n + SCAN_B - 1) / SCAN_B;   // 98 scan blocks

    // workspace layout (bytes):
    //   Abf: n*128 bf16 (25.6MB) | H: n*128 f32 (51.2MB) | Bbf: n*128 bf16 (25.6MB)
    //   | eidx[E] | row_ptr[n+1] | deg[n] | pos[n] | bsum[128]          (~110 MB)
    // C (n*40 f32, 16MB) aliases Abf; Dg (16MB) aliases Bbf — both free post-layer-1.
    ushort_t* Abf     = (ushort_t*)d_ws;
    float*    H       = (float*)(Abf + (size_t)n * DIM);
    ushort_t* Bbf     = (ushort_t*)(H + (size_t)n * DIM);
    int*      eidx    = (int*)(Bbf + (size_t)n * DIM);
    int*      row_ptr = eidx + E;
    int*      deg     = row_ptr + (n + 1);
    int*      pos     = deg + n;
    int*      bsum    = pos + n;
    float*    C       = (float*)Abf;   // reuse after Abf consumed
    float*    Dg      = (float*)Bbf;   // reuse after Bbf consumed

    hipMemsetAsync(deg, 0, (size_t)n * sizeof(int), stream);

    // --- CSR build (sorted-by-dst edge buckets) ---
    hist_kernel <<<(E + 255) / 256, 256, 0, stream>>>(dst, deg, E);
    scan1_kernel<<<nb, 256, 0, stream>>>(deg, bsum, n);
    scan2_kernel<<<1, 64, 0, stream>>>(bsum, nb, row_ptr, n);
    scan3_kernel<<<nb, SCAN_B, 0, stream>>>(deg, bsum, row_ptr, pos, n);
    fill_kernel <<<2048, 256, 0, stream>>>(src, dst, pos, eidx, E, n);

    // --- layer 1 ---
    // y1 (bf16) = x @ W1_l
    gemm128_kernel<<<512, 256, 0, stream>>>(x, W1l, nullptr, nullptr, nullptr, Abf, n, 0);
    // Bbf = mean_{src in N(dst)} y1[src]
    {
        long long t = (long long)n * 32;
        gather128_kernel<<<(int)((t + 255) / 256), 256, 0, stream>>>(Abf, row_ptr, eidx, Bbf, n);
    }
    // h (fp32) = relu(x @ W1_r + Bbf + b1)
    gemm128_kernel<<<512, 256, 0, stream>>>(x, W1r, Bbf, b1, H, nullptr, n, 1);

    // --- layer 2 ---
    // C = h @ W2_l  (aliases Abf)
    y2_kernel<<<625, 320, 0, stream>>>(H, W2l, C, n);
    // Dg = mean_{src in N(dst)} C[src]  (aliases Bbf)
    {
        long long t = (long long)n * 10;
        gather40_kernel<<<(int)((t + 255) / 256), 256, 0, stream>>>(C, row_ptr, eidx, Dg, n);
    }
    // out = softmax(Dg + b2 + h @ W2_r)
    final_kernel<<<(n + 255) / 256, 256, 0, stream>>>(H, Dg, W2r, b2, out, n);
}

// Round 4
// 536.700 us; speedup vs baseline: 7.7082x; 1.1736x over previous
//
#include <hip/hip_runtime.h>

#define DIM 128
#define NCLS 40
#define SCAN_B 1024

typedef unsigned short ushort_t;
typedef __attribute__((ext_vector_type(8))) short bf16x8;
typedef __attribute__((ext_vector_type(4))) float f32x4;

__device__ __forceinline__ ushort_t f2b(float f) {
    union { float f; unsigned u; } v; v.f = f;
    unsigned r = v.u + 0x7FFFu + ((v.u >> 16) & 1u);   // round-to-nearest-even
    return (ushort_t)(r >> 16);
}

__device__ __forceinline__ float b2f(ushort_t b) {
    union { unsigned u; float f; } v; v.u = ((unsigned)b) << 16;
    return v.f;
}

// ---------------- CSR build ----------------

__global__ __launch_bounds__(256) void hist_kernel(const int* __restrict__ dst,
                                                   int* __restrict__ deg, int E) {
    int e = blockIdx.x * 256 + threadIdx.x;
    if (e < E) atomicAdd(&deg[dst[e]], 1);
}

__global__ __launch_bounds__(256) void scan1_kernel(const int* __restrict__ deg,
                                                    int* __restrict__ bsum, int n) {
    __shared__ int sh[256];
    int base = blockIdx.x * SCAN_B;
    int s = 0;
    for (int i = threadIdx.x; i < SCAN_B; i += 256) {
        int idx = base + i;
        if (idx < n) s += deg[idx];
    }
    sh[threadIdx.x] = s;
    __syncthreads();
    for (int off = 128; off > 0; off >>= 1) {
        if (threadIdx.x < off) sh[threadIdx.x] += sh[threadIdx.x + off];
        __syncthreads();
    }
    if (threadIdx.x == 0) bsum[blockIdx.x] = sh[0];
}

__global__ __launch_bounds__(64) void scan2_kernel(int* __restrict__ bsum, int nb,
                                                   int* __restrict__ row_ptr, int n) {
    if (threadIdx.x == 0 && blockIdx.x == 0) {
        int acc = 0;
        for (int b = 0; b < nb; ++b) { int v = bsum[b]; bsum[b] = acc; acc += v; }
        row_ptr[n] = acc;   // == E
    }
}

__global__ __launch_bounds__(SCAN_B) void scan3_kernel(const int* __restrict__ deg,
                                                       const int* __restrict__ bsum,
                                                       int* __restrict__ row_ptr,
                                                       int* __restrict__ pos, int n) {
    __shared__ int sh[SCAN_B];
    int i = blockIdx.x * SCAN_B + threadIdx.x;
    int v = (i < n) ? deg[i] : 0;
    sh[threadIdx.x] = v;
    __syncthreads();
    for (int off = 1; off < SCAN_B; off <<= 1) {
        int t = (threadIdx.x >= off) ? sh[threadIdx.x - off] : 0;
        __syncthreads();
        sh[threadIdx.x] += t;
        __syncthreads();
    }
    if (i < n) {
        int rp = sh[threadIdx.x] - v + bsum[blockIdx.x];
        row_ptr[i] = rp;
        pos[i] = rp;        // fill bumps pos directly -> absolute slot
    }
}

// XCD-aligned bucketed fill: blocks with blockIdx%8==b handle dst range b.
// Consecutive blockIdx round-robin across the 8 XCDs, so each ~E/8*4B eidx
// window is written by ONE XCD's L2 -> merged line evictions. Buckets touch
// disjoint pos/eidx entries -> no inter-bucket sync needed; if the XCD
// mapping heuristic is wrong this only affects speed, not correctness.
__global__ __launch_bounds__(256) void fill_kernel(const int* __restrict__ src,
                                                   const int* __restrict__ dst,
                                                   int* __restrict__ pos,
                                                   int* __restrict__ eidx,
                                                   int E, int n) {
    const int buck = blockIdx.x & 7;
    const int bsz = (n + 7) / 8;
    const int lo = buck * bsz;
    const int hi = lo + bsz;
    const int bid = blockIdx.x >> 3;
    const int nb  = gridDim.x >> 3;
    const int tid = bid * 256 + threadIdx.x;
    const int stride = nb * 256;
    for (int e = tid; e < E; e += stride) {
        int d = dst[e];
        if (d >= lo && d < hi) {
            int p = atomicAdd(&pos[d], 1);
            eidx[p] = src[e];
        }
    }
}

// ---------------- dtype prep ----------------

// xbf = bf16(x), vectorized float4 -> ushort4
__global__ __launch_bounds__(256) void cast_kernel(const float* __restrict__ x,
                                                   ushort_t* __restrict__ xbf,
                                                   int n4) {
    int i = blockIdx.x * 256 + threadIdx.x;
    if (i >= n4) return;
    float4 v = ((const float4*)x)[i];
    ushort4 o;
    o.x = f2b(v.x); o.y = f2b(v.y); o.z = f2b(v.z); o.w = f2b(v.w);
    ((ushort4*)xbf)[i] = o;
}

// Pack W = [W1r; W1l] (256x128 fp32) into per-lane MFMA B-fragment order, bf16.
// Layout: Wp[kc*4096 + t*512 + lane*8 + j] = B[k = kc*32 + (lane>>4)*8 + j]
//                                             [n = t*16 + (lane&15)]
__global__ __launch_bounds__(256) void packw_kernel(const float* __restrict__ W1r,
                                                    const float* __restrict__ W1l,
                                                    ushort_t* __restrict__ Wp) {
    int o = blockIdx.x * 256 + threadIdx.x;   // 0..32767
    if (o >= 256 * DIM) return;
    int j    = o & 7;
    int lane = (o >> 3) & 63;
    int t    = (o >> 9) & 7;
    int kc   = o >> 12;
    int k = kc * 32 + (lane >> 4) * 8 + j;
    int n = t * 16 + (lane & 15);
    float v = (k < DIM) ? W1r[k * DIM + n] : W1l[(k - DIM) * DIM + n];
    Wp[o] = f2b(v);
}

// ---------------- compute ----------------

// mxbf[node] = mean over CSR neighbors of xbf[src] (bf16 in, fp32 accum, bf16 out)
// 32 lanes per node, ushort4 (8B) per lane -> 256B/edge coalesced
__global__ __launch_bounds__(256) void gather128_kernel(
    const ushort_t* __restrict__ Ybf, const int* __restrict__ row_ptr,
    const int* __restrict__ eidx, ushort_t* __restrict__ Bbf, int n)
{
    int t = blockIdx.x * 256 + threadIdx.x;
    int node = t >> 5;
    if (node >= n) return;
    int q = t & 31;
    int j  = row_ptr[node];
    int je = row_ptr[node + 1];
    const float id = 1.0f / fmaxf((float)(je - j), 1.0f);
    float4 acc = make_float4(0.f, 0.f, 0.f, 0.f);
    for (; j + 1 < je; j += 2) {
        int s0 = eidx[j], s1 = eidx[j + 1];
        ushort4 v0 = ((const ushort4*)(Ybf + (size_t)s0 * DIM))[q];
        ushort4 v1 = ((const ushort4*)(Ybf + (size_t)s1 * DIM))[q];
        acc.x += b2f(v0.x) + b2f(v1.x);
        acc.y += b2f(v0.y) + b2f(v1.y);
        acc.z += b2f(v0.z) + b2f(v1.z);
        acc.w += b2f(v0.w) + b2f(v1.w);
    }
    if (j < je) {
        int s0 = eidx[j];
        ushort4 v0 = ((const ushort4*)(Ybf + (size_t)s0 * DIM))[q];
        acc.x += b2f(v0.x); acc.y += b2f(v0.y); acc.z += b2f(v0.z); acc.w += b2f(v0.w);
    }
    ushort4 o;
    o.x = f2b(acc.x * id); o.y = f2b(acc.y * id);
    o.z = f2b(acc.z * id); o.w = f2b(acc.w * id);
    ((ushort4*)(Bbf + (size_t)node * DIM))[q] = o;
}

// H = relu([xbf | mxbf] @ Wp + b1), fp32 out. K=256 (8 chunks of 32).
// Block = 4 waves; each wave computes a 16-row x 128-col strip via 8 MFMA accums.
// No LDS: A frags direct from global (16 rows x 64B lines), B frags from the
// packed 64KB Wp table (same addresses for all blocks -> L2-resident).
__global__ __launch_bounds__(256) void mfma_gemm_kernel(
    const ushort_t* __restrict__ xbf, const ushort_t* __restrict__ mxbf,
    const ushort_t* __restrict__ Wp, const float* __restrict__ bias,
    float* __restrict__ H, int n)
{
    const int wave = threadIdx.x >> 6;
    const int lane = threadIdx.x & 63;
    const int m16  = lane & 15;
    const int quad = lane >> 4;
    const int row0 = blockIdx.x * 64 + wave * 16;
    int arow = row0 + m16;
    if (arow >= n) arow = n - 1;          // clamp; OOB rows never stored
    f32x4 acc[8];
    #pragma unroll
    for (int t = 0; t < 8; ++t) acc[t] = (f32x4){0.f, 0.f, 0.f, 0.f};
    const ushort_t* __restrict__ xrow = xbf  + (size_t)arow * DIM;
    const ushort_t* __restrict__ mrow = mxbf + (size_t)arow * DIM;
    #pragma unroll
    for (int kc = 0; kc < 8; ++kc) {
        const int kcol = (kc & 3) * 32 + quad * 8;
        const bf16x8 afrag = *(const bf16x8*)((kc < 4 ? xrow : mrow) + kcol);
        const ushort_t* __restrict__ wp = Wp + (size_t)kc * 4096 + (size_t)lane * 8;
        #pragma unroll
        for (int t = 0; t < 8; ++t) {
            const bf16x8 bfrag = *(const bf16x8*)(wp + (size_t)t * 512);
            acc[t] = __builtin_amdgcn_mfma_f32_16x16x32_bf16(afrag, bfrag, acc[t], 0, 0, 0);
        }
    }
    // C/D layout: col = t*16 + (lane&15), row = row0 + quad*4 + r
    #pragma unroll
    for (int t = 0; t < 8; ++t) {
        const int col = t * 16 + m16;
        const float bv = bias[col];
        #pragma unroll
        for (int r = 0; r < 4; ++r) {
            const int row = row0 + quad * 4 + r;
            if (row < n) H[(size_t)row * DIM + col] = fmaxf(acc[t][r] + bv, 0.f);
        }
    }
}

// Dg[node] = mean over CSR neighbors of C[src]; 10 lanes per node (float4 each)
__global__ __launch_bounds__(256) void gather40_kernel(
    const float* __restrict__ C, const int* __restrict__ row_ptr,
    const int* __restrict__ eidx, float* __restrict__ Dg, int n)
{
    int t = blockIdx.x * 256 + threadIdx.x;
    int node = t / 10;
    if (node >= n) return;
    int q = t - node * 10;
    int j  = row_ptr[node];
    int je = row_ptr[node + 1];
    const float id = 1.0f / fmaxf((float)(je - j), 1.0f);
    float4 acc = make_float4(0.f, 0.f, 0.f, 0.f);
    for (; j + 1 < je; j += 2) {
        int s0 = eidx[j], s1 = eidx[j + 1];
        float4 v0 = ((const float4*)(C + (size_t)s0 * NCLS))[q];
        float4 v1 = ((const float4*)(C + (size_t)s1 * NCLS))[q];
        acc.x += v0.x + v1.x;
        acc.y += v0.y + v1.y;
        acc.z += v0.z + v1.z;
        acc.w += v0.w + v1.w;
    }
    if (j < je) {
        int s0 = eidx[j];
        float4 v0 = ((const float4*)(C + (size_t)s0 * NCLS))[q];
        acc.x += v0.x; acc.y += v0.y; acc.z += v0.z; acc.w += v0.w;
    }
    acc.x *= id; acc.y *= id; acc.z *= id; acc.w *= id;
    ((float4*)(Dg + (size_t)node * NCLS))[q] = acc;
}

// C = H @ W2_l  (128x40, W in LDS). block 320 = 40 cols x 8 row-groups; 4 rows/thread.
__global__ __launch_bounds__(320) void y2_kernel(
    const float* __restrict__ H, const float* __restrict__ W,
    float* __restrict__ C, int n)
{
    __shared__ float Ws[DIM * NCLS];   // 20 KB
    for (int i = threadIdx.x; i < DIM * NCLS; i += 320) Ws[i] = W[i];
    __syncthreads();
    const int col = threadIdx.x % NCLS;
    const int ry  = threadIdx.x / NCLS;   // 0..7
    for (int base = blockIdx.x * 32; base < n; base += gridDim.x * 32) {
        const int r = base + ry * 4;      // n % 32 == 0 for N=100000
        const float* __restrict__ h0 = H + (size_t)(r + 0) * DIM;
        const float* __restrict__ h1 = H + (size_t)(r + 1) * DIM;
        const float* __restrict__ h2 = H + (size_t)(r + 2) * DIM;
        const float* __restrict__ h3 = H + (size_t)(r + 3) * DIM;
        float a0 = 0.f, a1 = 0.f, a2 = 0.f, a3 = 0.f;
        #pragma unroll 4
        for (int k = 0; k < DIM; k += 4) {
            const float4 v0 = *(const float4*)(h0 + k);
            const float4 v1 = *(const float4*)(h1 + k);
            const float4 v2 = *(const float4*)(h2 + k);
            const float4 v3 = *(const float4*)(h3 + k);
            const float w0 = Ws[(k + 0) * NCLS + col];
            const float w1 = Ws[(k + 1) * NCLS + col];
            const float w2 = Ws[(k + 2) * NCLS + col];
            const float w3 = Ws[(k + 3) * NCLS + col];
            a0 = fmaf(v0.x, w0, fmaf(v0.y, w1, fmaf(v0.z, w2, fmaf(v0.w, w3, a0))));
            a1 = fmaf(v1.x, w0, fmaf(v1.y, w1, fmaf(v1.z, w2, fmaf(v1.w, w3, a1))));
            a2 = fmaf(v2.x, w0, fmaf(v2.y, w1, fmaf(v2.z, w2, fmaf(v2.w, w3, a2))));
            a3 = fmaf(v3.x, w0, fmaf(v3.y, w1, fmaf(v3.z, w2, fmaf(v3.w, w3, a3))));
        }
        C[(size_t)(r + 0) * NCLS + col] = a0;
        C[(size_t)(r + 1) * NCLS + col] = a1;
        C[(size_t)(r + 2) * NCLS + col] = a2;
        C[(size_t)(r + 3) * NCLS + col] = a3;
    }
}

// out = softmax(Agg + b2 + H @ W2_r), one thread per node (40 logits in regs)
__global__ __launch_bounds__(256) void final_kernel(
    const float* __restrict__ H, const float* __restrict__ Agg,
    const float* __restrict__ W, const float* __restrict__ b2,
    float* __restrict__ out, int n)
{
    int nd = blockIdx.x * 256 + threadIdx.x;
    if (nd >= n) return;
    float lg[NCLS];
    const float* __restrict__ ag = Agg + (size_t)nd * NCLS;
    #pragma unroll
    for (int c = 0; c < NCLS; ++c) lg[c] = ag[c] + b2[c];
    const float* __restrict__ h = H + (size_t)nd * DIM;
    for (int k = 0; k < DIM; k += 4) {
        const float4 hv = *(const float4*)(h + k);
        const float* __restrict__ w0 = W + (size_t)(k + 0) * NCLS;  // uniform -> s_load
        const float* __restrict__ w1 = W + (size_t)(k + 1) * NCLS;
        const float* __restrict__ w2 = W + (size_t)(k + 2) * NCLS;
        const float* __restrict__ w3 = W + (size_t)(k + 3) * NCLS;
        #pragma unroll
        for (int c = 0; c < NCLS; ++c) {
            float acc = lg[c];
            acc = fmaf(hv.x, w0[c], acc);
            acc = fmaf(hv.y, w1[c], acc);
            acc = fmaf(hv.z, w2[c], acc);
            acc = fmaf(hv.w, w3[c], acc);
            lg[c] = acc;
        }
    }
    float m = lg[0];
    #pragma unroll
    for (int c = 1; c < NCLS; ++c) m = fmaxf(m, lg[c]);
    float s = 0.f;
    #pragma unroll
    for (int c = 0; c < NCLS; ++c) { lg[c] = __expf(lg[c] - m); s += lg[c]; }
    const float inv = 1.0f / s;
    float* __restrict__ o = out + (size_t)nd * NCLS;
    #pragma unroll
    for (int c = 0; c < NCLS; ++c) o[c] = lg[c] * inv;
}

extern "C" void kernel_launch(void* const* d_in, const int* in_sizes, int n_in,
                              void* d_out, int out_size, void* d_ws, size_t ws_size,
                              hipStream_t stream) {
    const float* x   = (const float*)d_in[0];
    const int*   ei  = (const int*)d_in[1];
    const float* W1l = (const float*)d_in[2];
    const float* W1r = (const float*)d_in[3];
    const float* b1  = (const float*)d_in[4];
    const float* W2l = (const float*)d_in[5];
    const float* W2r = (const float*)d_in[6];
    const float* b2  = (const float*)d_in[7];
    float* out = (float*)d_out;

    const int n = in_sizes[0] / DIM;   // 100000
    const int E = in_sizes[1] / 2;     // 1600000
    const int* src = ei;
    const int* dst = ei + E;
    const int nb = (n + SCAN_B - 1) / SCAN_B;   // 98 scan blocks

    // workspace layout:
    //   xbf: n*128 bf16 (25.6MB) | mxbf: n*128 bf16 (25.6MB) | H: n*128 f32 (51.2MB)
    //   | Wp: 256*128 bf16 (64KB) | eidx[E] | row_ptr[n+1] | deg[n] | pos[n] | bsum[128]
    // C (n*40 f32) aliases xbf; Dg aliases mxbf — both free after mfma_gemm.
    ushort_t* xbf     = (ushort_t*)d_ws;
    ushort_t* mxbf    = xbf + (size_t)n * DIM;
    float*    H       = (float*)(mxbf + (size_t)n * DIM);
    ushort_t* Wp      = (ushort_t*)(H + (size_t)n * DIM);
    int*      eidx    = (int*)(Wp + 256 * DIM);
    int*      row_ptr = eidx + E;
    int*      deg     = row_ptr + (n + 1);
    int*      pos     = deg + n;
    int*      bsum    = pos + n;
    float*    C       = (float*)xbf;    // reuse after layer-1 GEMM
    float*    Dg      = (float*)mxbf;   // reuse after layer-1 GEMM

    hipMemsetAsync(deg, 0, (size_t)n * sizeof(int), stream);

    // --- CSR build + dtype prep ---
    hist_kernel <<<(E + 255) / 256, 256, 0, stream>>>(dst, deg, E);
    scan1_kernel<<<nb, 256, 0, stream>>>(deg, bsum, n);
    scan2_kernel<<<1, 64, 0, stream>>>(bsum, nb, row_ptr, n);
    scan3_kernel<<<nb, SCAN_B, 0, stream>>>(deg, bsum, row_ptr, pos, n);
    fill_kernel <<<2048, 256, 0, stream>>>(src, dst, pos, eidx, E, n);
    cast_kernel <<<(n * 32 + 255) / 256, 256, 0, stream>>>(x, xbf, n * 32);
    packw_kernel<<<128, 256, 0, stream>>>(W1r, W1l, Wp);

    // --- layer 1 ---
    // mxbf = mean_{src in N(dst)} xbf[src]
    {
        long long t = (long long)n * 32;
        gather128_kernel<<<(int)((t + 255) / 256), 256, 0, stream>>>(xbf, row_ptr, eidx, mxbf, n);
    }
    // H = relu([xbf | mxbf] @ [W1r; W1l] + b1)
    mfma_gemm_kernel<<<(n + 63) / 64, 256, 0, stream>>>(xbf, mxbf, Wp, b1, H, n);

    // --- layer 2 ---
    // C = H @ W2_l  (aliases xbf)
    y2_kernel<<<625, 320, 0, stream>>>(H, W2l, C, n);
    // Dg = mean_{src in N(dst)} C[src]  (aliases mxbf)
    {
        long long t = (long long)n * 10;
        gather40_kernel<<<(int)((t + 255) / 256), 256, 0, stream>>>(C, row_ptr, eidx, Dg, n);
    }
    // out = softmax(Dg + b2 + H @ W2_r)
    final_kernel<<<(n + 255) / 256, 256, 0, stream>>>(H, Dg, W2r, b2, out, n);
}

// Round 6
// 462.495 us; speedup vs baseline: 8.9449x; 1.1604x over previous
//
#include <hip/hip_runtime.h>

#define DIM 128
#define NCLS 40
#define SCAN_B 1024

typedef unsigned short ushort_t;
typedef __attribute__((ext_vector_type(8))) short bf16x8;
typedef __attribute__((ext_vector_type(4))) float f32x4;

__device__ __forceinline__ ushort_t f2b(float f) {
    union { float f; unsigned u; } v; v.f = f;
    unsigned r = v.u + 0x7FFFu + ((v.u >> 16) & 1u);   // round-to-nearest-even
    return (ushort_t)(r >> 16);
}

__device__ __forceinline__ float b2f(ushort_t b) {
    union { unsigned u; float f; } v; v.u = ((unsigned)b) << 16;
    return v.f;
}

// ---------------- CSR build ----------------

__global__ __launch_bounds__(256) void hist_kernel(const int* __restrict__ dst,
                                                   int* __restrict__ deg, int E) {
    int e = blockIdx.x * 256 + threadIdx.x;
    if (e < E) atomicAdd(&deg[dst[e]], 1);
}

__global__ __launch_bounds__(256) void scan1_kernel(const int* __restrict__ deg,
                                                    int* __restrict__ bsum, int n) {
    __shared__ int sh[256];
    int base = blockIdx.x * SCAN_B;
    int s = 0;
    for (int i = threadIdx.x; i < SCAN_B; i += 256) {
        int idx = base + i;
        if (idx < n) s += deg[idx];
    }
    sh[threadIdx.x] = s;
    __syncthreads();
    for (int off = 128; off > 0; off >>= 1) {
        if (threadIdx.x < off) sh[threadIdx.x] += sh[threadIdx.x + off];
        __syncthreads();
    }
    if (threadIdx.x == 0) bsum[blockIdx.x] = sh[0];
}

__global__ __launch_bounds__(64) void scan2_kernel(int* __restrict__ bsum, int nb,
                                                   int* __restrict__ row_ptr, int n) {
    if (threadIdx.x == 0 && blockIdx.x == 0) {
        int acc = 0;
        for (int b = 0; b < nb; ++b) { int v = bsum[b]; bsum[b] = acc; acc += v; }
        row_ptr[n] = acc;   // == E
    }
}

__global__ __launch_bounds__(SCAN_B) void scan3_kernel(const int* __restrict__ deg,
                                                       const int* __restrict__ bsum,
                                                       int* __restrict__ row_ptr,
                                                       int* __restrict__ pos, int n) {
    __shared__ int sh[SCAN_B];
    int i = blockIdx.x * SCAN_B + threadIdx.x;
    int v = (i < n) ? deg[i] : 0;
    sh[threadIdx.x] = v;
    __syncthreads();
    for (int off = 1; off < SCAN_B; off <<= 1) {
        int t = (threadIdx.x >= off) ? sh[threadIdx.x - off] : 0;
        __syncthreads();
        sh[threadIdx.x] += t;
        __syncthreads();
    }
    if (i < n) {
        int rp = sh[threadIdx.x] - v + bsum[blockIdx.x];
        row_ptr[i] = rp;
        pos[i] = rp;        // fill bumps pos directly -> absolute slot
    }
}

// XCD-aligned bucketed fill: blocks with blockIdx%8==b handle dst range b.
__global__ __launch_bounds__(256) void fill_kernel(const int* __restrict__ src,
                                                   const int* __restrict__ dst,
                                                   int* __restrict__ pos,
                                                   int* __restrict__ eidx,
                                                   int E, int n) {
    const int buck = blockIdx.x & 7;
    const int bsz = (n + 7) / 8;
    const int lo = buck * bsz;
    const int hi = lo + bsz;
    const int bid = blockIdx.x >> 3;
    const int nb  = gridDim.x >> 3;
    const int tid = bid * 256 + threadIdx.x;
    const int stride = nb * 256;
    for (int e = tid; e < E; e += stride) {
        int d = dst[e];
        if (d >= lo && d < hi) {
            int p = atomicAdd(&pos[d], 1);
            eidx[p] = src[e];
        }
    }
}

// ---------------- dtype prep ----------------

__global__ __launch_bounds__(256) void cast_kernel(const float* __restrict__ x,
                                                   ushort_t* __restrict__ xbf,
                                                   int n4) {
    int i = blockIdx.x * 256 + threadIdx.x;
    if (i >= n4) return;
    float4 v = ((const float4*)x)[i];
    ushort4 o;
    o.x = f2b(v.x); o.y = f2b(v.y); o.z = f2b(v.z); o.w = f2b(v.w);
    ((ushort4*)xbf)[i] = o;
}

// Pack W = [W1r; W1l] (256x128 fp32) into per-lane MFMA B-fragment order, bf16.
// Wp[kc*4096 + t*512 + lane*8 + j] = B[k = kc*32 + (lane>>4)*8 + j][n = t*16 + (lane&15)]
__global__ __launch_bounds__(256) void packw_kernel(const float* __restrict__ W1r,
                                                    const float* __restrict__ W1l,
                                                    ushort_t* __restrict__ Wp) {
    int o = blockIdx.x * 256 + threadIdx.x;   // 0..32767
    if (o >= 256 * DIM) return;
    int j    = o & 7;
    int lane = (o >> 3) & 63;
    int t    = (o >> 9) & 7;
    int kc   = o >> 12;
    int k = kc * 32 + (lane >> 4) * 8 + j;
    int n = t * 16 + (lane & 15);
    float v = (k < DIM) ? W1r[k * DIM + n] : W1l[(k - DIM) * DIM + n];
    Wp[o] = f2b(v);
}

// Pack W2_l (128x40 fp32) into B-fragment order, bf16, cols zero-padded to 48.
// Wp2[kc*1536 + t*512 + lane*8 + j] = W2l[k = kc*32 + (lane>>4)*8 + j][n = t*16 + (lane&15)]
__global__ __launch_bounds__(256) void packw2_kernel(const float* __restrict__ W2l,
                                                     ushort_t* __restrict__ Wp2) {
    int o = blockIdx.x * 256 + threadIdx.x;   // 0..6143
    if (o >= 4 * 1536) return;
    int j    = o & 7;
    int lane = (o >> 3) & 63;
    int rem  = o >> 9;
    int t    = rem % 3;
    int kc   = rem / 3;
    int k  = kc * 32 + (lane >> 4) * 8 + j;
    int nn = t * 16 + (lane & 15);
    Wp2[o] = (nn < NCLS) ? f2b(W2l[k * NCLS + nn]) : (ushort_t)0;
}

// ---------------- compute ----------------

// mxbf[node] = mean over CSR neighbors of xbf[src]
__global__ __launch_bounds__(256) void gather128_kernel(
    const ushort_t* __restrict__ Ybf, const int* __restrict__ row_ptr,
    const int* __restrict__ eidx, ushort_t* __restrict__ Bbf, int n)
{
    int t = blockIdx.x * 256 + threadIdx.x;
    int node = t >> 5;
    if (node >= n) return;
    int q = t & 31;
    int j  = row_ptr[node];
    int je = row_ptr[node + 1];
    const float id = 1.0f / fmaxf((float)(je - j), 1.0f);
    float4 acc = make_float4(0.f, 0.f, 0.f, 0.f);
    for (; j + 1 < je; j += 2) {
        int s0 = eidx[j], s1 = eidx[j + 1];
        ushort4 v0 = ((const ushort4*)(Ybf + (size_t)s0 * DIM))[q];
        ushort4 v1 = ((const ushort4*)(Ybf + (size_t)s1 * DIM))[q];
        acc.x += b2f(v0.x) + b2f(v1.x);
        acc.y += b2f(v0.y) + b2f(v1.y);
        acc.z += b2f(v0.z) + b2f(v1.z);
        acc.w += b2f(v0.w) + b2f(v1.w);
    }
    if (j < je) {
        int s0 = eidx[j];
        ushort4 v0 = ((const ushort4*)(Ybf + (size_t)s0 * DIM))[q];
        acc.x += b2f(v0.x); acc.y += b2f(v0.y); acc.z += b2f(v0.z); acc.w += b2f(v0.w);
    }
    ushort4 o;
    o.x = f2b(acc.x * id); o.y = f2b(acc.y * id);
    o.z = f2b(acc.z * id); o.w = f2b(acc.w * id);
    ((ushort4*)(Bbf + (size_t)node * DIM))[q] = o;
}

// Fused layer-1 + layer-2-left:
//   h  = relu([xbf | mxbf] @ Wp + b1)          (K=256, 8 MFMA accums/wave)
//   Hbf = bf16(h)  (coalesced dwordx4 stores via LDS readback regs)
//   C  = h @ W2_l  (per-wave LDS transpose -> 12 MFMAs vs packed Wp2)
// Block = 4 waves x 16 rows. Per-wave LDS tile: no __syncthreads needed.
__global__ __launch_bounds__(256) void mfma_gemm_kernel(
    const ushort_t* __restrict__ xbf, const ushort_t* __restrict__ mxbf,
    const ushort_t* __restrict__ Wp, const ushort_t* __restrict__ Wp2,
    const float* __restrict__ bias,
    ushort_t* __restrict__ Hbf, float* __restrict__ C, int n)
{
    __shared__ ushort_t hl[4][16 * 136];   // 16 rows x 136 (pad 8) bf16 per wave
    const int wave = threadIdx.x >> 6;
    const int lane = threadIdx.x & 63;
    const int m16  = lane & 15;
    const int quad = lane >> 4;
    const int row0 = blockIdx.x * 64 + wave * 16;
    int arow = row0 + m16;
    if (arow >= n) arow = n - 1;          // clamp; OOB rows never stored
    f32x4 acc[8];
    #pragma unroll
    for (int t = 0; t < 8; ++t) acc[t] = (f32x4){0.f, 0.f, 0.f, 0.f};
    const ushort_t* __restrict__ xrow = xbf  + (size_t)arow * DIM;
    const ushort_t* __restrict__ mrow = mxbf + (size_t)arow * DIM;
    #pragma unroll
    for (int kc = 0; kc < 8; ++kc) {
        const int kcol = (kc & 3) * 32 + quad * 8;
        const bf16x8 afrag = *(const bf16x8*)((kc < 4 ? xrow : mrow) + kcol);
        const ushort_t* __restrict__ wp = Wp + (size_t)kc * 4096 + (size_t)lane * 8;
        #pragma unroll
        for (int t = 0; t < 8; ++t) {
            const bf16x8 bfrag = *(const bf16x8*)(wp + (size_t)t * 512);
            acc[t] = __builtin_amdgcn_mfma_f32_16x16x32_bf16(afrag, bfrag, acc[t], 0, 0, 0);
        }
    }
    // epilogue 1: relu+bias, stage h tile (bf16) into this wave's LDS region.
    // C/D layout: col = t*16 + m16, row = quad*4 + r (block-local + row0)
    ushort_t* __restrict__ hw = hl[wave];
    #pragma unroll
    for (int t = 0; t < 8; ++t) {
        const int col = t * 16 + m16;
        const float bv = bias[col];
        #pragma unroll
        for (int r = 0; r < 4; ++r) {
            hw[(quad * 4 + r) * 136 + col] = f2b(fmaxf(acc[t][r] + bv, 0.f));
        }
    }
    // second GEMM: C_tile = h_tile @ W2_l   (K=128 -> 4 chunks)
    f32x4 acc2[3];
    #pragma unroll
    for (int t = 0; t < 3; ++t) acc2[t] = (f32x4){0.f, 0.f, 0.f, 0.f};
    const bool rowok = (row0 + m16) < n;
    #pragma unroll
    for (int kc = 0; kc < 4; ++kc) {
        // A-frag readback: A[m=m16][k = kc*32 + quad*8 + j]
        const bf16x8 afrag2 = *(const bf16x8*)(hw + m16 * 136 + kc * 32 + quad * 8);
        // doubles as the coalesced Hbf store (row m16, 16B per lane)
        if (rowok)
            *(bf16x8*)(Hbf + (size_t)(row0 + m16) * DIM + kc * 32 + quad * 8) = afrag2;
        const ushort_t* __restrict__ wp2 = Wp2 + (size_t)kc * 1536 + (size_t)lane * 8;
        #pragma unroll
        for (int t = 0; t < 3; ++t) {
            const bf16x8 bfrag = *(const bf16x8*)(wp2 + (size_t)t * 512);
            acc2[t] = __builtin_amdgcn_mfma_f32_16x16x32_bf16(afrag2, bfrag, acc2[t], 0, 0, 0);
        }
    }
    #pragma unroll
    for (int t = 0; t < 3; ++t) {
        const int col = t * 16 + m16;
        if (col >= NCLS) continue;
        #pragma unroll
        for (int r = 0; r < 4; ++r) {
            const int row = row0 + quad * 4 + r;
            if (row < n) C[(size_t)row * NCLS + col] = acc2[t][r];
        }
    }
}

// Dg[node] = mean over CSR neighbors of C[src]; 10 lanes per node (float4 each)
__global__ __launch_bounds__(256) void gather40_kernel(
    const float* __restrict__ C, const int* __restrict__ row_ptr,
    const int* __restrict__ eidx, float* __restrict__ Dg, int n)
{
    int t = blockIdx.x * 256 + threadIdx.x;
    int node = t / 10;
    if (node >= n) return;
    int q = t - node * 10;
    int j  = row_ptr[node];
    int je = row_ptr[node + 1];
    const float id = 1.0f / fmaxf((float)(je - j), 1.0f);
    float4 acc = make_float4(0.f, 0.f, 0.f, 0.f);
    for (; j + 1 < je; j += 2) {
        int s0 = eidx[j], s1 = eidx[j + 1];
        float4 v0 = ((const float4*)(C + (size_t)s0 * NCLS))[q];
        float4 v1 = ((const float4*)(C + (size_t)s1 * NCLS))[q];
        acc.x += v0.x + v1.x;
        acc.y += v0.y + v1.y;
        acc.z += v0.z + v1.z;
        acc.w += v0.w + v1.w;
    }
    if (j < je) {
        int s0 = eidx[j];
        float4 v0 = ((const float4*)(C + (size_t)s0 * NCLS))[q];
        acc.x += v0.x; acc.y += v0.y; acc.z += v0.z; acc.w += v0.w;
    }
    acc.x *= id; acc.y *= id; acc.z *= id; acc.w *= id;
    ((float4*)(Dg + (size_t)node * NCLS))[q] = acc;
}

// out = softmax(Agg + b2 + Hbf @ W2_r), one thread per node (40 logits in regs)
__global__ __launch_bounds__(256) void final_kernel(
    const ushort_t* __restrict__ Hbf, const float* __restrict__ Agg,
    const float* __restrict__ W, const float* __restrict__ b2,
    float* __restrict__ out, int n)
{
    int nd = blockIdx.x * 256 + threadIdx.x;
    if (nd >= n) return;
    float lg[NCLS];
    const float* __restrict__ ag = Agg + (size_t)nd * NCLS;
    #pragma unroll
    for (int c = 0; c < NCLS; ++c) lg[c] = ag[c] + b2[c];
    const ushort_t* __restrict__ h = Hbf + (size_t)nd * DIM;
    for (int k = 0; k < DIM; k += 4) {
        const ushort4 hu = *(const ushort4*)(h + k);
        const float hx = b2f(hu.x), hy = b2f(hu.y), hz = b2f(hu.z), hw = b2f(hu.w);
        const float* __restrict__ w0 = W + (size_t)(k + 0) * NCLS;
        const float* __restrict__ w1 = W + (size_t)(k + 1) * NCLS;
        const float* __restrict__ w2 = W + (size_t)(k + 2) * NCLS;
        const float* __restrict__ w3 = W + (size_t)(k + 3) * NCLS;
        #pragma unroll
        for (int c = 0; c < NCLS; ++c) {
            float acc = lg[c];
            acc = fmaf(hx, w0[c], acc);
            acc = fmaf(hy, w1[c], acc);
            acc = fmaf(hz, w2[c], acc);
            acc = fmaf(hw, w3[c], acc);
            lg[c] = acc;
        }
    }
    float m = lg[0];
    #pragma unroll
    for (int c = 1; c < NCLS; ++c) m = fmaxf(m, lg[c]);
    float s = 0.f;
    #pragma unroll
    for (int c = 0; c < NCLS; ++c) { lg[c] = __expf(lg[c] - m); s += lg[c]; }
    const float inv = 1.0f / s;
    float* __restrict__ o = out + (size_t)nd * NCLS;
    #pragma unroll
    for (int c = 0; c < NCLS; ++c) o[c] = lg[c] * inv;
}

extern "C" void kernel_launch(void* const* d_in, const int* in_sizes, int n_in,
                              void* d_out, int out_size, void* d_ws, size_t ws_size,
                              hipStream_t stream) {
    const float* x   = (const float*)d_in[0];
    const int*   ei  = (const int*)d_in[1];
    const float* W1l = (const float*)d_in[2];
    const float* W1r = (const float*)d_in[3];
    const float* b1  = (const float*)d_in[4];
    const float* W2l = (const float*)d_in[5];
    const float* W2r = (const float*)d_in[6];
    const float* b2  = (const float*)d_in[7];
    float* out = (float*)d_out;

    const int n = in_sizes[0] / DIM;   // 100000
    const int E = in_sizes[1] / 2;     // 1600000
    const int* src = ei;
    const int* dst = ei + E;
    const int nb = (n + SCAN_B - 1) / SCAN_B;   // 98 scan blocks

    // workspace layout:
    //   xbf (25.6MB) | mxbf (25.6MB) | Hbf (25.6MB bf16) | C (16MB f32)
    //   | Wp (64KB) | Wp2 (12KB) | eidx[E] | row_ptr[n+1] | deg[n] | pos[n] | bsum[128]
    // Dg aliases mxbf (free after mfma_gemm consumes it).
    ushort_t* xbf     = (ushort_t*)d_ws;
    ushort_t* mxbf    = xbf + (size_t)n * DIM;
    ushort_t* Hbf     = mxbf + (size_t)n * DIM;
    float*    C       = (float*)(Hbf + (size_t)n * DIM);
    ushort_t* Wp      = (ushort_t*)(C + (size_t)n * NCLS);
    ushort_t* Wp2     = Wp + 256 * DIM;
    int*      eidx    = (int*)(Wp2 + 4 * 1536);
    int*      row_ptr = eidx + E;
    int*      deg     = row_ptr + (n + 1);
    int*      pos     = deg + n;
    int*      bsum    = pos + n;
    float*    Dg      = (float*)mxbf;   // reuse after mfma_gemm

    (void)hipMemsetAsync(deg, 0, (size_t)n * sizeof(int), stream);

    // --- CSR build + dtype prep ---
    hist_kernel  <<<(E + 255) / 256, 256, 0, stream>>>(dst, deg, E);
    scan1_kernel <<<nb, 256, 0, stream>>>(deg, bsum, n);
    scan2_kernel <<<1, 64, 0, stream>>>(bsum, nb, row_ptr, n);
    scan3_kernel <<<nb, SCAN_B, 0, stream>>>(deg, bsum, row_ptr, pos, n);
    fill_kernel  <<<2048, 256, 0, stream>>>(src, dst, pos, eidx, E, n);
    cast_kernel  <<<(n * 32 + 255) / 256, 256, 0, stream>>>(x, xbf, n * 32);
    packw_kernel <<<128, 256, 0, stream>>>(W1r, W1l, Wp);
    packw2_kernel<<<24, 256, 0, stream>>>(W2l, Wp2);

    // --- layer 1 + layer-2-left (fused) ---
    {
        long long t = (long long)n * 32;
        gather128_kernel<<<(int)((t + 255) / 256), 256, 0, stream>>>(xbf, row_ptr, eidx, mxbf, n);
    }
    mfma_gemm_kernel<<<(n + 63) / 64, 256, 0, stream>>>(xbf, mxbf, Wp, Wp2, b1, Hbf, C, n);

    // --- layer 2 ---
    {
        long long t = (long long)n * 10;
        gather40_kernel<<<(int)((t + 255) / 256), 256, 0, stream>>>(C, row_ptr, eidx, Dg, n);
    }
    final_kernel<<<(n + 255) / 256, 256, 0, stream>>>(Hbf, Dg, W2r, b2, out, n);
}